// Round 1
// baseline (1411.358 us; speedup 1.0000x reference)
//
#include <hip/hip_runtime.h>

#define B_ 128
#define T_ 270
#define XR 4104   // 8 + 64*64

typedef __attribute__((ext_vector_type(8))) short short8v;
typedef __attribute__((ext_vector_type(4))) float f32x4;

__device__ inline unsigned short f2bf(float f) {
  unsigned u = __builtin_bit_cast(unsigned, f);
  u += 0x7fffu + ((u >> 16) & 1u);
  return (unsigned short)(u >> 16);
}
__device__ inline float sigm(float x) { return 1.0f / (1.0f + __expf(-x)); }
__device__ inline float tanh_f(float x) {
  float t = __expf(-2.0f * fabsf(x));
  float r = (1.0f - t) / (1.0f + t);
  return copysignf(r, x);
}

// ---------------------------------------------------------------------------
// Kernel 1: per-(b,t) CNN tower. One block per image.
// conv1(1->2,3x3)+relu+maxpool4 -> conv2(2->4,3x3)+relu+maxpool4 -> fc(36->8)
// Writes feat[t][b][16] = concat(x_ns[8], fc_out[8]).
// Also zeroes the LSTM barrier counters and initializes out[] = head_b.
// ---------------------------------------------------------------------------
__global__ __launch_bounds__(256) void cnn_kernel(
    const float* __restrict__ x,
    const float* __restrict__ c1w_, const float* __restrict__ c1b_,
    const float* __restrict__ c2w_, const float* __restrict__ c2b_,
    const float* __restrict__ fcw, const float* __restrict__ fcb,
    const float* __restrict__ hdb,
    float* __restrict__ feat, unsigned* __restrict__ ctr,
    float* __restrict__ out)
{
  __shared__ float img[64 * 68];      // 64x64 image, row pad to 68
  __shared__ float p1[2 * 15 * 16];   // pooled conv1, row pad to 16
  __shared__ float p2[36];
  __shared__ float wsm[96];           // w1(18) b1(2) w2(72) b2(4)
  const int tid = threadIdx.x;
  const int bt = blockIdx.x;
  const int b = bt & 127, t = bt >> 7;

  if (bt == 0 && tid < 128) ctr[tid] = 0;   // zero barrier counters each launch

  const float* src = x + ((long)b * T_ + t) * XR;

  if (tid < 18) wsm[tid] = c1w_[tid];
  else if (tid < 20) wsm[tid] = c1b_[tid - 18];
  else if (tid < 92) wsm[tid] = c2w_[tid - 20];
  else if (tid < 96) wsm[tid] = c2b_[tid - 92];

  {
    const float4* s4 = (const float4*)(src + 8);
#pragma unroll
    for (int i0 = 0; i0 < 4; i0++) {
      int i = tid + i0 * 256;
      float4 v = s4[i];
      int e = i * 4;
      *((float4*)&img[(e >> 6) * 68 + (e & 63)]) = v;
    }
  }
  __syncthreads();

  // conv1 + relu + pool (both channels per thread; cells y<=59,x<=59 only)
  if (tid < 225) {
    int py = tid / 15, px = tid - (tid / 15) * 15;
    float w0[9], w1[9];
#pragma unroll
    for (int j = 0; j < 9; j++) { w0[j] = wsm[j]; w1[j] = wsm[9 + j]; }
    const float b0 = wsm[18], b1v = wsm[19];
    float m0 = -1e30f, m1 = -1e30f;
    for (int dy = 0; dy < 4; dy++) {
      for (int dx = 0; dx < 4; dx++) {
        const float* ip = &img[(py * 4 + dy) * 68 + px * 4 + dx];
        float s0 = b0, s1 = b1v;
#pragma unroll
        for (int ky = 0; ky < 3; ky++) {
#pragma unroll
          for (int kx = 0; kx < 3; kx++) {
            float v = ip[ky * 68 + kx];
            s0 = fmaf(v, w0[ky * 3 + kx], s0);
            s1 = fmaf(v, w1[ky * 3 + kx], s1);
          }
        }
        m0 = fmaxf(m0, s0); m1 = fmaxf(m1, s1);
      }
    }
    p1[py * 16 + px] = fmaxf(m0, 0.f);
    p1[240 + py * 16 + px] = fmaxf(m1, 0.f);
  }
  __syncthreads();

  // conv2 + relu + pool  (4 x 3 x 3 = 36 outputs)
  if (tid < 36) {
    int ch = tid / 9, rem = tid - ch * 9;
    int py = rem / 3, px = rem - py * 3;
    float m = -1e30f;
    for (int dy = 0; dy < 4; dy++) {
      for (int dx = 0; dx < 4; dx++) {
        int y = py * 4 + dy, xx = px * 4 + dx;
        float s = wsm[92 + ch];
#pragma unroll
        for (int ic = 0; ic < 2; ic++)
#pragma unroll
          for (int ky = 0; ky < 3; ky++)
#pragma unroll
            for (int kx = 0; kx < 3; kx++)
              s = fmaf(p1[ic * 240 + (y + ky) * 16 + xx + kx],
                       wsm[20 + ((ch * 2 + ic) * 3 + ky) * 3 + kx], s);
        m = fmaxf(m, s);
      }
    }
    p2[tid] = fmaxf(m, 0.f);
  }
  __syncthreads();

  float* fr = feat + ((long)t * B_ + b) * 16;
  if (tid < 8) {
    float s = fcb[tid];
#pragma unroll
    for (int j = 0; j < 36; j++) s = fmaf(p2[j], fcw[tid * 36 + j], s);
    fr[8 + tid] = s;
  } else if (tid < 16) {
    fr[tid - 8] = src[tid - 8];            // x_ns passthrough
  } else if (tid == 16) {
    out[(long)b * T_ + t] = hdb[0];        // init output with head bias
  }
}

// ---------------------------------------------------------------------------
// Kernel 2: LSTM recurrence, 32 blocks = 8 batch-groups(16 rows) x 4 hidden
// tiles(64 dims). w_hh/w_ih held as bf16 MFMA B-fragments in VGPRs for all
// 270 steps. h exchanged via agent-scope (cache-bypass) atomics + 4-block
// flag barrier per batch group. Head projection fused via atomicAdd.
// ---------------------------------------------------------------------------
__global__ __launch_bounds__(256, 1) void lstm_kernel(
    const float* __restrict__ feat, const float* __restrict__ whh,
    const float* __restrict__ wih, const float* __restrict__ bih,
    const float* __restrict__ bhh, const float* __restrict__ h0,
    const float* __restrict__ c0, const float* __restrict__ hw,
    unsigned* hb0, unsigned* hb1, unsigned* ctr, float* __restrict__ out)
{
  const int tid = threadIdx.x;
  const int wv = tid >> 6, lane = tid & 63;
  const int gb = blockIdx.x >> 2;       // batch group 0..7  (rows gb*16..+15)
  const int hbk = blockIdx.x & 3;       // hidden tile 0..3  (dims hbk*64..+63)
  const int R0 = gb * 16, D0 = hbk * 64;
  __shared__ float gates[16 * 256];
  __shared__ float bias[256];
  unsigned* cptr = ctr + gb * 16;

  {
    int tau = tid >> 6, dl = tid & 63;
    int gr = tau * 256 + D0 + dl;
    bias[tid] = bih[gr] + bhh[gr];
  }

  // ---- B-fragments: wave wv = gate type wv, cols nt*16+(lane&15) of 64 dims.
  const int col15 = lane & 15, ko = (lane >> 4) * 8;
  short8v bf[4][9];
  for (int nt = 0; nt < 4; nt++) {
    int gr = wv * 256 + D0 + nt * 16 + col15;
    const float* wr = whh + gr * 256;
#pragma unroll
    for (int kf = 0; kf < 8; kf++) {
      const float4* wp = (const float4*)(wr + kf * 32 + ko);
      float4 a = wp[0], bq = wp[1];
      short8v v;
      v[0] = f2bf(a.x); v[1] = f2bf(a.y); v[2] = f2bf(a.z); v[3] = f2bf(a.w);
      v[4] = f2bf(bq.x); v[5] = f2bf(bq.y); v[6] = f2bf(bq.z); v[7] = f2bf(bq.w);
      bf[nt][kf] = v;
    }
    short8v v = {0, 0, 0, 0, 0, 0, 0, 0};
    if (ko < 16) {   // 9th K-frag: w_ih (K slots 256..271), rest zero
      const float4* wp = (const float4*)(wih + gr * 16 + ko);
      float4 a = wp[0], bq = wp[1];
      v[0] = f2bf(a.x); v[1] = f2bf(a.y); v[2] = f2bf(a.z); v[3] = f2bf(a.w);
      v[4] = f2bf(bq.x); v[5] = f2bf(bq.y); v[6] = f2bf(bq.z); v[7] = f2bf(bq.w);
    }
    bf[nt][8] = v;
  }

  // ---- elementwise-thread mapping: rows er+{0,8}, dims dl2,dl2+1
  const int dl2 = (tid & 31) * 2, er = tid >> 5;
  float cst[2][2];
#pragma unroll
  for (int p = 0; p < 2; p++) {
    int r = er + 8 * p;
    cst[p][0] = c0[(R0 + r) * 256 + D0 + dl2];
    cst[p][1] = c0[(R0 + r) * 256 + D0 + dl2 + 1];
    unsigned lo = f2bf(h0[(R0 + r) * 256 + D0 + dl2]);
    unsigned hi = f2bf(h0[(R0 + r) * 256 + D0 + dl2 + 1]);
    __hip_atomic_store(hb0 + (R0 + r) * 128 + ((D0 + dl2) >> 1), lo | (hi << 16),
                       __ATOMIC_RELAXED, __HIP_MEMORY_SCOPE_AGENT);
  }

  unsigned* hbr = hb0;
  unsigned* hbw = hb1;
  unsigned target = 4;

  // init barrier (h0 slices visible to group)
  __syncthreads();
  if (tid == 0) {
    __hip_atomic_fetch_add(cptr, 1u, __ATOMIC_ACQ_REL, __HIP_MEMORY_SCOPE_AGENT);
    long guard = 0;
    while (__hip_atomic_load(cptr, __ATOMIC_ACQUIRE, __HIP_MEMORY_SCOPE_AGENT) < target &&
           ++guard < (1L << 22)) {}
  }
  __syncthreads();

  const int ar = lane & 15;   // A-fragment row (batch row within tile)

  for (int t = 0; t < T_; t++) {
    // ---- A-fragments: full h row (bypass loads) + feat as 9th frag
    short8v af[9];
    const unsigned long long* hrow =
        (const unsigned long long*)(hbr + (R0 + ar) * 128);
#pragma unroll
    for (int kf = 0; kf < 8; kf++) {
      int kq = kf * 8 + (ko >> 2);
      union { unsigned long long q[2]; short8v s; } u;
      u.q[0] = __hip_atomic_load(hrow + kq, __ATOMIC_RELAXED, __HIP_MEMORY_SCOPE_AGENT);
      u.q[1] = __hip_atomic_load(hrow + kq + 1, __ATOMIC_RELAXED, __HIP_MEMORY_SCOPE_AGENT);
      af[kf] = u.s;
    }
    {
      short8v v = {0, 0, 0, 0, 0, 0, 0, 0};
      if (ko < 16) {
        const float4* fp = (const float4*)(feat + ((long)t * B_ + R0 + ar) * 16 + ko);
        float4 a = fp[0], bq = fp[1];
        v[0] = f2bf(a.x); v[1] = f2bf(a.y); v[2] = f2bf(a.z); v[3] = f2bf(a.w);
        v[4] = f2bf(bq.x); v[5] = f2bf(bq.y); v[6] = f2bf(bq.z); v[7] = f2bf(bq.w);
      }
      af[8] = v;
    }

    f32x4 acc[4];
#pragma unroll
    for (int nt = 0; nt < 4; nt++) acc[nt] = (f32x4){0.f, 0.f, 0.f, 0.f};
#pragma unroll
    for (int kf = 0; kf < 9; kf++)
#pragma unroll
      for (int nt = 0; nt < 4; nt++)
        acc[nt] = __builtin_amdgcn_mfma_f32_16x16x32_bf16(af[kf], bf[nt][kf], acc[nt], 0, 0, 0);

    const int rb = (lane >> 4) * 4;
#pragma unroll
    for (int nt = 0; nt < 4; nt++)
#pragma unroll
      for (int rr = 0; rr < 4; rr++)
        gates[(rb + rr) * 256 + wv * 64 + nt * 16 + col15] = acc[nt][rr];
    __syncthreads();

    // ---- elementwise LSTM cell + fused head partial
#pragma unroll
    for (int p = 0; p < 2; p++) {
      int r = er + 8 * p;
      float hn2[2];
#pragma unroll
      for (int j = 0; j < 2; j++) {
        int dl = dl2 + j;
        float ipre = gates[r * 256 + dl] + bias[dl];
        float fpre = gates[r * 256 + 64 + dl] + bias[64 + dl];
        float gpre = gates[r * 256 + 128 + dl] + bias[128 + dl];
        float opre = gates[r * 256 + 192 + dl] + bias[192 + dl];
        float cn = sigm(fpre) * cst[p][j] + sigm(ipre) * tanh_f(gpre);
        cst[p][j] = cn;
        hn2[j] = sigm(opre) * tanh_f(cn);
      }
      unsigned pk = (unsigned)f2bf(hn2[0]) | ((unsigned)f2bf(hn2[1]) << 16);
      __hip_atomic_store(hbw + (R0 + r) * 128 + ((D0 + dl2) >> 1), pk,
                         __ATOMIC_RELAXED, __HIP_MEMORY_SCOPE_AGENT);
      float s = hn2[0] * hw[D0 + dl2] + hn2[1] * hw[D0 + dl2 + 1];
#pragma unroll
      for (int off = 16; off >= 1; off >>= 1) s += __shfl_xor(s, off);
      if ((lane & 31) == 0) atomicAdd(&out[(long)(R0 + r) * T_ + t], s);
    }

    { unsigned* tmp = hbr; hbr = hbw; hbw = tmp; }
    target += 4;
    __syncthreads();
    if (tid == 0) {
      __hip_atomic_fetch_add(cptr, 1u, __ATOMIC_ACQ_REL, __HIP_MEMORY_SCOPE_AGENT);
      long guard = 0;
      while (__hip_atomic_load(cptr, __ATOMIC_ACQUIRE, __HIP_MEMORY_SCOPE_AGENT) < target &&
             ++guard < (1L << 22)) {}
    }
    __syncthreads();
  }
}

// ---------------------------------------------------------------------------
extern "C" void kernel_launch(void* const* d_in, const int* in_sizes, int n_in,
                              void* d_out, int out_size, void* d_ws, size_t ws_size,
                              hipStream_t stream) {
  const float* x   = (const float*)d_in[0];
  const float* c1w = (const float*)d_in[1];
  const float* c1b = (const float*)d_in[2];
  const float* c2w = (const float*)d_in[3];
  const float* c2b = (const float*)d_in[4];
  const float* fcw = (const float*)d_in[5];
  const float* fcb = (const float*)d_in[6];
  const float* wih = (const float*)d_in[7];
  const float* whh = (const float*)d_in[8];
  const float* bih = (const float*)d_in[9];
  const float* bhh = (const float*)d_in[10];
  const float* hw  = (const float*)d_in[11];
  const float* hdb = (const float*)d_in[12];
  const float* h0  = (const float*)d_in[13];
  const float* c0  = (const float*)d_in[14];
  float* out = (float*)d_out;

  char* ws = (char*)d_ws;
  // layout: feat fp32 [270][128][16] | hbuf0 | hbuf1 (bf16 pairs as u32) | ctr
  const size_t FEAT_B = (size_t)T_ * B_ * 16 * 4;          // 2,211,840
  const size_t HBUF_B = (size_t)B_ * 128 * 4;              // 65,536 (u32 per 2 dims)
  if (ws_size < FEAT_B + 2 * HBUF_B + 512) return;
  float* feat   = (float*)ws;
  unsigned* hb0 = (unsigned*)(ws + FEAT_B);
  unsigned* hb1 = (unsigned*)(ws + FEAT_B + HBUF_B);
  unsigned* ctr = (unsigned*)(ws + FEAT_B + 2 * HBUF_B);

  cnn_kernel<<<dim3(B_ * T_), dim3(256), 0, stream>>>(
      x, c1w, c1b, c2w, c2b, fcw, fcb, hdb, feat, ctr, out);
  lstm_kernel<<<dim3(32), dim3(256), 0, stream>>>(
      feat, whh, wih, bih, bhh, h0, c0, hw, hb0, hb1, ctr, out);
}